// Round 23
// baseline (753.038 us; speedup 1.0000x reference)
//
#include <hip/hip_runtime.h>

#define DIM 64
#define NPB 256          // nodes per bucket (bucket id = dst >> 8)
#define MAXBUCK 512      // N up to 131072
#define CHUNK 4096       // edges per binning block (R17: 1024 -> atomic storm)
#define BCAP 8192        // fixed bucket capacity (mean 4092, +64 sigma safe)
#define BSTRIDE 16       // bcur padding: 1 counter per 64B line (R17 lesson)

__device__ __forceinline__ unsigned short f2bf(float v) {
    unsigned u = __float_as_uint(v);
    unsigned r = (u + 0x7fffu + ((u >> 16) & 1u)) >> 16;  // RNE
    return (unsigned short)r;
}

// Fat kernel: blocks [0, binB) run edge binning; blocks [binB, ...) run matmul.
__global__ void __launch_bounds__(256)
fused_mm_bin(const float* __restrict__ x, const float* __restrict__ W,
             unsigned short* __restrict__ hbf, int N,
             const int* __restrict__ ei, int* __restrict__ bcur,
             unsigned* __restrict__ binned, int E, int nbuck, int binB) {
    __shared__ __align__(16) char buf[(DIM * DIM + DIM * 68) * 4];  // 33 KB
    int tid = threadIdx.x;

    if (blockIdx.x < binB) {
        int* hist = (int*)buf;
        long e0 = (long)blockIdx.x * CHUNK;
        for (int i = tid; i < nbuck; i += 256) hist[i] = 0;
        __syncthreads();
        int s[16], t[16];
#pragma unroll
        for (int it = 0; it < 16; ++it) {
            long e = e0 + it * 256 + tid;
            if (e < E) {
                s[it] = ei[e];
                t[it] = ei[E + e];
                atomicAdd(&hist[t[it] >> 8], 1);
            } else {
                s[it] = -1;
            }
        }
        __syncthreads();
        for (int i = tid; i < nbuck; i += 256) {
            int c = hist[i];
            hist[i] = c ? (i * BCAP + atomicAdd(&bcur[i * BSTRIDE], c)) : 0;
        }
        __syncthreads();
#pragma unroll
        for (int it = 0; it < 16; ++it) {
            if (s[it] >= 0) {
                int b = t[it] >> 8;
                int p = atomicAdd(&hist[b], 1);
                binned[p] = ((unsigned)s[it] << 8) | (unsigned)(t[it] & 255);
            }
        }
        return;
    }

    // matmul: thread = 4 nodes x 4 dims (unroll capped — R14 spill lesson)
    float* Wl = (float*)buf;
    float (*xsT)[68] = (float(*)[68])(buf + DIM * DIM * 4);
    for (int i = tid; i < 1024; i += 256)
        ((float4*)Wl)[i] = ((const float4*)W)[i];
    int node0 = (blockIdx.x - binB) * 64;
#pragma unroll
    for (int rep = 0; rep < 4; ++rep) {
        int i = rep * 256 + tid;
        int nn = i >> 4, c4 = (i & 15) * 4;
        int gn = node0 + nn;
        float4 v;
        if (gn < N) v = *(const float4*)(x + (long)gn * DIM + c4);
        else { v.x = v.y = v.z = v.w = 0.f; }
        xsT[c4 + 0][nn] = v.x;
        xsT[c4 + 1][nn] = v.y;
        xsT[c4 + 2][nn] = v.z;
        xsT[c4 + 3][nn] = v.w;
    }
    __syncthreads();

    int lane = tid & 63, wv_ = tid >> 6;
    int d4 = (lane & 15) * 4;
    int n0 = wv_ * 16 + (lane >> 4) * 4;
    float4 a0, a1, a2, a3;
    a0.x = a0.y = a0.z = a0.w = 0.f;
    a1.x = a1.y = a1.z = a1.w = 0.f;
    a2.x = a2.y = a2.z = a2.w = 0.f;
    a3.x = a3.y = a3.z = a3.w = 0.f;
#pragma unroll 2
    for (int k = 0; k < DIM; ++k) {
        float4 wr = *(const float4*)&Wl[k * DIM + d4];
        float4 xv = *(const float4*)&xsT[k][n0];
        a0.x += xv.x * wr.x; a0.y += xv.x * wr.y; a0.z += xv.x * wr.z; a0.w += xv.x * wr.w;
        a1.x += xv.y * wr.x; a1.y += xv.y * wr.y; a1.z += xv.y * wr.z; a1.w += xv.y * wr.w;
        a2.x += xv.z * wr.x; a2.y += xv.z * wr.y; a2.z += xv.z * wr.z; a2.w += xv.z * wr.w;
        a3.x += xv.w * wr.x; a3.y += xv.w * wr.y; a3.z += xv.w * wr.z; a3.w += xv.w * wr.w;
    }
#define STORE_NODE(j, aj)                                                   \
    {                                                                       \
        int gn = node0 + n0 + j;                                            \
        if (gn < N) {                                                       \
            uint2 p;                                                       \
            p.x = (unsigned)f2bf(aj.x) | ((unsigned)f2bf(aj.y) << 16);      \
            p.y = (unsigned)f2bf(aj.z) | ((unsigned)f2bf(aj.w) << 16);      \
            *(uint2*)(hbf + (long)gn * DIM + d4) = p;                       \
        }                                                                   \
    }
    STORE_NODE(0, a0) STORE_NODE(1, a1) STORE_NODE(2, a2) STORE_NODE(3, a3)
#undef STORE_NODE
}

// per-bucket: node-degree histogram (-> dinv) + 16-way seg sort (key src>>13)
__global__ void seg_sort(const int* __restrict__ bcur, const unsigned* __restrict__ binned,
                         unsigned* __restrict__ binned2, float* __restrict__ dinv, int N) {
    __shared__ int nodeHist[NPB];
    __shared__ int segCnt[16];
    __shared__ int segCur[16];
    int b = blockIdx.x, tid = threadIdx.x;  // 512
    int cnt = bcur[b * BSTRIDE];
    int e0 = b * BCAP, e1 = e0 + cnt;
    if (tid < NPB) nodeHist[tid] = 0;
    if (tid < 16) segCnt[tid] = 0;
    __syncthreads();
    for (int e = e0 + tid; e < e1; e += 512) {
        unsigned u = binned[e];
        atomicAdd(&nodeHist[u & 255], 1);
        atomicAdd(&segCnt[u >> 21], 1);  // seg = src >> 13
    }
    __syncthreads();
    if (tid == 0) {
        int run = e0;
        for (int sgi = 0; sgi < 16; ++sgi) { segCur[sgi] = run; run += segCnt[sgi]; }
    }
    int node = (b << 8) + tid;
    if (tid < NPB && node < N) dinv[node] = rsqrtf((float)nodeHist[tid] + 1.f);
    __syncthreads();
    for (int e = e0 + tid; e < e1; e += 512) {
        unsigned u = binned[e];
        int p = atomicAdd(&segCur[u >> 21], 1);
        binned2[p] = u;
    }
}

// Seg-major LDS aggregate: block = (bucket, feature-half). Edges sorted by src
// segment -> all blocks sweep segments roughly in phase -> src-row reads hit L2.
// acc[256][33] padded: bank = (row + 2*f2) % 32 spreads 4-edge groups.
__global__ void __launch_bounds__(512)
aggregate(const int* __restrict__ bcur, const unsigned* __restrict__ binned2,
          const unsigned* __restrict__ hb, const float* __restrict__ dinv,
          const float2* __restrict__ x2, const float2* __restrict__ b2,
          float2* __restrict__ o2, int N) {
    __shared__ float acc[NPB][33];   // 33.8 KB -> 4 blocks/CU
    int b = blockIdx.x >> 1, h = blockIdx.x & 1;
    int tid = threadIdx.x;           // 512
    int lane = tid & 63, wid = tid >> 6;
    for (int i = tid; i < NPB * 33; i += 512) ((float*)acc)[i] = 0.f;
    __syncthreads();
    int cnt = bcur[b * BSTRIDE];
    int e0 = b * BCAP, e1 = e0 + cnt;
    int eslot = lane >> 4, f2 = lane & 15;
    const unsigned* hbh = hb + h * 16;   // half-row base (row stride 32 uints)

    for (int c = e0 + wid * 64; c < e1; c += 512) {
        int take = e1 - c; if (take > 64) take = 64;
        unsigned u = (lane < take) ? binned2[c + lane] : 0u;
        int s = u >> 8;
        int r = u & 255;
        float w = (lane < take) ? dinv[s] : 0.f;
        // 16 edges per step: 4 groups x 4 edges; 4 row loads in flight
        for (int j = 0; j < take; j += 16) {
            int i0 = j + 0 + eslot, i1 = j + 4 + eslot;
            int i2 = j + 8 + eslot, i3 = j + 12 + eslot;
            int t0 = __shfl(s, i0), t1 = __shfl(s, i1), t2 = __shfl(s, i2), t3 = __shfl(s, i3);
            int r0 = __shfl(r, i0), r1 = __shfl(r, i1), r2 = __shfl(r, i2), r3 = __shfl(r, i3);
            float q0 = __shfl(w, i0), q1 = __shfl(w, i1), q2 = __shfl(w, i2), q3 = __shfl(w, i3);
            unsigned h0 = hbh[(long)t0 * 32 + f2];
            unsigned h1 = hbh[(long)t1 * 32 + f2];
            unsigned h2 = hbh[(long)t2 * 32 + f2];
            unsigned h3 = hbh[(long)t3 * 32 + f2];
#define PUT(hu, rr, qq)                                                       \
            atomicAdd(&acc[rr][2 * f2],     __uint_as_float(hu << 16) * qq);  \
            atomicAdd(&acc[rr][2 * f2 + 1], __uint_as_float(hu & 0xffff0000u) * qq);
            PUT(h0, r0, q0) PUT(h1, r1, q1) PUT(h2, r2, q2) PUT(h3, r3, q3)
#undef PUT
        }
    }
    __syncthreads();
    // epilogue: 256 nodes x 16 float2 for this half; self-loop + bias + relu + residual
    for (int i = tid; i < NPB * 16; i += 512) {
        int rr = i >> 4, q = i & 15;
        int n = (b << 8) + rr;
        if (n >= N) continue;
        float dn = dinv[n];
        unsigned su = hbh[(long)n * 32 + q];
        float a0 = acc[rr][2 * q]     + __uint_as_float(su << 16) * dn;
        float a1 = acc[rr][2 * q + 1] + __uint_as_float(su & 0xffff0000u) * dn;
        long gi = (long)n * 32 + h * 16 + q;
        float2 bb = b2[h * 16 + q];
        float2 xx = x2[gi];
        float2 rv;
        rv.x = xx.x + fmaxf(a0 * dn + bb.x, 0.f);
        rv.y = xx.y + fmaxf(a1 * dn + bb.y, 0.f);
        o2[gi] = rv;
    }
}

extern "C" void kernel_launch(void* const* d_in, const int* in_sizes, int n_in,
                              void* d_out, int out_size, void* d_ws, size_t ws_size,
                              hipStream_t stream) {
    const float* x = (const float*)d_in[0];
    const int* ei  = (const int*)d_in[1];
    const float* W = (const float*)d_in[2];
    const float* b = (const float*)d_in[3];
    float* out = (float*)d_out;

    int N = in_sizes[0] / DIM;
    int E = in_sizes[1] / 2;
    int nbuck = (N + NPB - 1) / NPB;  // 391

    char* ws = (char*)d_ws;
    size_t o = 0;
    unsigned short* hbf = (unsigned short*)(ws + o); o += (size_t)N * DIM * sizeof(unsigned short);
    float* dinv  = (float*)(ws + o); o += (size_t)N * sizeof(float);
    int*   bcur  = (int*)(ws + o);   o += (size_t)nbuck * BSTRIDE * sizeof(int);
    unsigned* binned  = (unsigned*)(ws + o); o += (size_t)nbuck * BCAP * sizeof(unsigned);
    unsigned* binned2 = (unsigned*)(ws + o); o += (size_t)nbuck * BCAP * sizeof(unsigned);

    int binB = (E + CHUNK - 1) / CHUNK;          // 391 binning blocks (first)
    int mmB  = (N + 63) / 64;                    // 1563 matmul blocks

    hipMemsetAsync(bcur, 0, (size_t)nbuck * BSTRIDE * sizeof(int), stream);
    fused_mm_bin<<<binB + mmB, 256, 0, stream>>>(x, W, hbf, N, ei, bcur,
                                                 binned, E, nbuck, binB);
    seg_sort<<<nbuck, 512, 0, stream>>>(bcur, binned, binned2, dinv, N);
    aggregate<<<nbuck * 2, 512, 0, stream>>>(bcur, binned2, (const unsigned*)hbf, dinv,
                                             (const float2*)x, (const float2*)b,
                                             (float2*)out, N);
}

// Round 24
// 102.498 us; speedup vs baseline: 7.3469x; 7.3469x over previous
//
#include <hip/hip_runtime.h>

#define DIM 64
#define NPB 256          // nodes per bucket (bucket id = dst >> 8)
#define MAXBUCK 512      // N up to 131072
#define CHUNK 4096       // edges per binning block (R17: 1024 -> atomic storm)
#define BCAP 8192        // fixed bucket capacity (mean 4092, +64 sigma safe)
#define BSTRIDE 16       // bcur padding: 1 counter per 64B line (R17 lesson)

__device__ __forceinline__ unsigned short f2bf(float v) {
    unsigned u = __float_as_uint(v);
    unsigned r = (u + 0x7fffu + ((u >> 16) & 1u)) >> 16;  // RNE
    return (unsigned short)r;
}

// Fat kernel: blocks [0, binB) run edge binning; blocks [binB, ...) run matmul.
// The two phases are data-independent (matmul: x,W->hbf; bin: ei->binned) and
// overlap here instead of serializing on the stream. LDS aliased via buf.
__global__ void __launch_bounds__(256)
fused_mm_bin(const float* __restrict__ x, const float* __restrict__ W,
             unsigned short* __restrict__ hbf, int N,
             const int* __restrict__ ei, int* __restrict__ bcur,
             unsigned* __restrict__ binned, int E, int nbuck, int binB) {
    __shared__ __align__(16) char buf[(DIM * DIM + DIM * 68) * 4];  // 33 KB
    int tid = threadIdx.x;

    if (blockIdx.x < binB) {
        // ---- edge binning (bucket regions at i*BCAP; cursors memset to 0) ----
        int* hist = (int*)buf;
        long e0 = (long)blockIdx.x * CHUNK;
        for (int i = tid; i < nbuck; i += 256) hist[i] = 0;
        __syncthreads();
        int s[16], t[16];
#pragma unroll
        for (int it = 0; it < 16; ++it) {
            long e = e0 + it * 256 + tid;
            if (e < E) {
                s[it] = ei[e];
                t[it] = ei[E + e];
                atomicAdd(&hist[t[it] >> 8], 1);
            } else {
                s[it] = -1;
            }
        }
        __syncthreads();
        // reserve contiguous range per (block,bucket); hist -> global cursor
        for (int i = tid; i < nbuck; i += 256) {
            int c = hist[i];
            hist[i] = c ? (i * BCAP + atomicAdd(&bcur[i * BSTRIDE], c)) : 0;
        }
        __syncthreads();
#pragma unroll
        for (int it = 0; it < 16; ++it) {
            if (s[it] >= 0) {
                int b = t[it] >> 8;
                int p = atomicAdd(&hist[b], 1);
                binned[p] = ((unsigned)s[it] << 8) | (unsigned)(t[it] & 255);
            }
        }
        return;
    }

    // ---- matmul: thread = 4 nodes x 4 dims; per k: 2x ds_read_b128 + 16 FMA.
    // unroll capped (R14: full unroll -> VGPR spill -> 1 GB scratch traffic).
    float* Wl = (float*)buf;                       // [64][64]
    float (*xsT)[68] = (float(*)[68])(buf + DIM * DIM * 4);  // [64][68]
    for (int i = tid; i < 1024; i += 256)
        ((float4*)Wl)[i] = ((const float4*)W)[i];
    int node0 = (blockIdx.x - binB) * 64;
#pragma unroll
    for (int rep = 0; rep < 4; ++rep) {
        int i = rep * 256 + tid;
        int nn = i >> 4, c4 = (i & 15) * 4;
        int gn = node0 + nn;
        float4 v;
        if (gn < N) v = *(const float4*)(x + (long)gn * DIM + c4);
        else { v.x = v.y = v.z = v.w = 0.f; }
        xsT[c4 + 0][nn] = v.x;
        xsT[c4 + 1][nn] = v.y;
        xsT[c4 + 2][nn] = v.z;
        xsT[c4 + 3][nn] = v.w;
    }
    __syncthreads();

    int lane = tid & 63, wv_ = tid >> 6;
    int d4 = (lane & 15) * 4;
    int n0 = wv_ * 16 + (lane >> 4) * 4;
    float4 a0, a1, a2, a3;
    a0.x = a0.y = a0.z = a0.w = 0.f;
    a1.x = a1.y = a1.z = a1.w = 0.f;
    a2.x = a2.y = a2.z = a2.w = 0.f;
    a3.x = a3.y = a3.z = a3.w = 0.f;
#pragma unroll 2
    for (int k = 0; k < DIM; ++k) {
        float4 wr = *(const float4*)&Wl[k * DIM + d4];
        float4 xv = *(const float4*)&xsT[k][n0];
        a0.x += xv.x * wr.x; a0.y += xv.x * wr.y; a0.z += xv.x * wr.z; a0.w += xv.x * wr.w;
        a1.x += xv.y * wr.x; a1.y += xv.y * wr.y; a1.z += xv.y * wr.z; a1.w += xv.y * wr.w;
        a2.x += xv.z * wr.x; a2.y += xv.z * wr.y; a2.z += xv.z * wr.z; a2.w += xv.z * wr.w;
        a3.x += xv.w * wr.x; a3.y += xv.w * wr.y; a3.z += xv.w * wr.z; a3.w += xv.w * wr.w;
    }
#define STORE_NODE(j, aj)                                                   \
    {                                                                       \
        int gn = node0 + n0 + j;                                            \
        if (gn < N) {                                                       \
            uint2 p;                                                       \
            p.x = (unsigned)f2bf(aj.x) | ((unsigned)f2bf(aj.y) << 16);      \
            p.y = (unsigned)f2bf(aj.z) | ((unsigned)f2bf(aj.w) << 16);      \
            *(uint2*)(hbf + (long)gn * DIM + d4) = p;                       \
        }                                                                   \
    }
    STORE_NODE(0, a0) STORE_NODE(1, a1) STORE_NODE(2, a2) STORE_NODE(3, a3)
#undef STORE_NODE
}

// per-bucket LDS counting sort -> gapped per-node CSR (adj, off, ncnt, dinv)
__global__ void bucket_sort(const int* __restrict__ bcur, const unsigned* __restrict__ binned,
                            int* __restrict__ off, int* __restrict__ ncnt,
                            int* __restrict__ adj, float* __restrict__ dinv, int N) {
    __shared__ int lcur[NPB];
    __shared__ int sh[NPB];
    int bid = blockIdx.x, tid = threadIdx.x;  // 512 threads
    int node0 = bid << 8;
    int e0 = bid * BCAP;
    int e1 = e0 + bcur[bid * BSTRIDE];        // zero-based cursor = bucket count
    if (tid < NPB) lcur[tid] = 0;
    __syncthreads();
    for (int e = e0 + tid; e < e1; e += 512)
        atomicAdd(&lcur[binned[e] & 255], 1);
    __syncthreads();
    int v = 0;
    if (tid < NPB) { v = lcur[tid]; sh[tid] = v; }
    __syncthreads();
    for (int d = 1; d < NPB; d <<= 1) {
        int t = (tid < NPB && tid >= d) ? sh[tid - d] : 0;
        __syncthreads();
        if (tid < NPB) sh[tid] += t;
        __syncthreads();
    }
    if (tid < NPB) {
        int excl = sh[tid] - v;
        lcur[tid] = excl;
        int node = node0 + tid;
        if (node < N) {
            off[node] = e0 + excl;
            ncnt[node] = v;
            dinv[node] = rsqrtf((float)v + 1.0f);
        }
    }
    __syncthreads();
    for (int e = e0 + tid; e < e1; e += 512) {
        unsigned u = binned[e];
        int p = atomicAdd(&lcur[u & 255], 1);
        adj[e0 + p] = (int)(u >> 8);
    }
}

// TWO nodes per wave: 16 hb loads in flight (2 independent 8-load streams).
// At the random-fetch floor (~104 MB, R20/R21/R23 confirmed) — do not touch.
__global__ void gather_agg(const int* __restrict__ off, const int* __restrict__ ncnt,
                           const int* __restrict__ adj,
                           const unsigned* __restrict__ hb, const float* __restrict__ dinv,
                           const float2* __restrict__ x2, const float2* __restrict__ b2,
                           float2* __restrict__ o2, int N) {
    int wid = threadIdx.x >> 6;
    int lane = threadIdx.x & 63;
    int nodeA = blockIdx.x * 8 + wid * 2;
    int nodeB = nodeA + 1;
    if (nodeA >= N) return;
    bool hasB = (nodeB < N);
    int sub = lane >> 5;
    int f = lane & 31;
    int startA = off[nodeA];
    int mA = ncnt[nodeA];
    int startB = hasB ? off[nodeB] : 0;
    int mB = hasB ? ncnt[nodeB] : 0;
    float dnA = dinv[nodeA];
    float dnB = hasB ? dinv[nodeB] : 0.f;
    unsigned usA = hb[(long)nodeA * 32 + f];
    unsigned usB = hasB ? hb[(long)nodeB * 32 + f] : 0u;
    float2 accA; accA.x = 0.f; accA.y = 0.f;
    float2 accB; accB.x = 0.f; accB.y = 0.f;

    int mmax = mA > mB ? mA : mB;
    for (int c = 0; c < mmax; c += 64) {
        int takeA = mA - c; if (takeA > 64) takeA = 64;
        int takeB = mB - c; if (takeB > 64) takeB = 64;
        int sA = (lane < takeA) ? adj[startA + c + lane] : 0;
        float wA = (lane < takeA) ? dinv[sA] : 0.f;
        int sB = (lane < takeB) ? adj[startB + c + lane] : 0;
        float wB = (lane < takeB) ? dinv[sB] : 0.f;
        int tmax = takeA > takeB ? takeA : takeB;
        for (int i = 0; i < tmax; i += 16) {
            unsigned uA0 = 0, uA1 = 0, uA2 = 0, uA3 = 0, uA4 = 0, uA5 = 0, uA6 = 0, uA7 = 0;
            unsigned uB0 = 0, uB1 = 0, uB2 = 0, uB3 = 0, uB4 = 0, uB5 = 0, uB6 = 0, uB7 = 0;
            float qA0 = 0, qA1 = 0, qA2 = 0, qA3 = 0, qA4 = 0, qA5 = 0, qA6 = 0, qA7 = 0;
            float qB0 = 0, qB1 = 0, qB2 = 0, qB3 = 0, qB4 = 0, qB5 = 0, qB6 = 0, qB7 = 0;
            if (i < takeA) {
                int i0 = i + 0 + sub, i1 = i + 2 + sub, i2 = i + 4 + sub, i3 = i + 6 + sub;
                int i4 = i + 8 + sub, i5 = i + 10 + sub, i6 = i + 12 + sub, i7 = i + 14 + sub;
                int t0 = __shfl(sA, i0), t1 = __shfl(sA, i1), t2 = __shfl(sA, i2), t3 = __shfl(sA, i3);
                int t4 = __shfl(sA, i4), t5 = __shfl(sA, i5), t6 = __shfl(sA, i6), t7 = __shfl(sA, i7);
                qA0 = __shfl(wA, i0); qA1 = __shfl(wA, i1); qA2 = __shfl(wA, i2); qA3 = __shfl(wA, i3);
                qA4 = __shfl(wA, i4); qA5 = __shfl(wA, i5); qA6 = __shfl(wA, i6); qA7 = __shfl(wA, i7);
                uA0 = hb[(long)t0 * 32 + f]; uA1 = hb[(long)t1 * 32 + f];
                uA2 = hb[(long)t2 * 32 + f]; uA3 = hb[(long)t3 * 32 + f];
                uA4 = hb[(long)t4 * 32 + f]; uA5 = hb[(long)t5 * 32 + f];
                uA6 = hb[(long)t6 * 32 + f]; uA7 = hb[(long)t7 * 32 + f];
            }
            if (i < takeB) {
                int i0 = i + 0 + sub, i1 = i + 2 + sub, i2 = i + 4 + sub, i3 = i + 6 + sub;
                int i4 = i + 8 + sub, i5 = i + 10 + sub, i6 = i + 12 + sub, i7 = i + 14 + sub;
                int t0 = __shfl(sB, i0), t1 = __shfl(sB, i1), t2 = __shfl(sB, i2), t3 = __shfl(sB, i3);
                int t4 = __shfl(sB, i4), t5 = __shfl(sB, i5), t6 = __shfl(sB, i6), t7 = __shfl(sB, i7);
                qB0 = __shfl(wB, i0); qB1 = __shfl(wB, i1); qB2 = __shfl(wB, i2); qB3 = __shfl(wB, i3);
                qB4 = __shfl(wB, i4); qB5 = __shfl(wB, i5); qB6 = __shfl(wB, i6); qB7 = __shfl(wB, i7);
                uB0 = hb[(long)t0 * 32 + f]; uB1 = hb[(long)t1 * 32 + f];
                uB2 = hb[(long)t2 * 32 + f]; uB3 = hb[(long)t3 * 32 + f];
                uB4 = hb[(long)t4 * 32 + f]; uB5 = hb[(long)t5 * 32 + f];
                uB6 = hb[(long)t6 * 32 + f]; uB7 = hb[(long)t7 * 32 + f];
            }
#define ACC(acc, u, q)                                                  \
            acc.x += __uint_as_float(u << 16) * q;                      \
            acc.y += __uint_as_float(u & 0xffff0000u) * q;
            ACC(accA, uA0, qA0) ACC(accA, uA1, qA1) ACC(accA, uA2, qA2) ACC(accA, uA3, qA3)
            ACC(accA, uA4, qA4) ACC(accA, uA5, qA5) ACC(accA, uA6, qA6) ACC(accA, uA7, qA7)
            ACC(accB, uB0, qB0) ACC(accB, uB1, qB1) ACC(accB, uB2, qB2) ACC(accB, uB3, qB3)
            ACC(accB, uB4, qB4) ACC(accB, uB5, qB5) ACC(accB, uB6, qB6) ACC(accB, uB7, qB7)
#undef ACC
        }
    }
    accA.x += __shfl_xor(accA.x, 32);
    accA.y += __shfl_xor(accA.y, 32);
    accB.x += __shfl_xor(accB.x, 32);
    accB.y += __shfl_xor(accB.y, 32);
    accA.x += __uint_as_float(usA << 16) * dnA;
    accA.y += __uint_as_float(usA & 0xffff0000u) * dnA;
    accB.x += __uint_as_float(usB << 16) * dnB;
    accB.y += __uint_as_float(usB & 0xffff0000u) * dnB;

    int wn = (lane < 32) ? nodeA : nodeB;
    float2 wacc = (lane < 32) ? accA : accB;
    float dnw = (lane < 32) ? dnA : dnB;
    if (wn < N) {
        long gi = (long)wn * 32 + f;
        float2 bb = b2[f];
        float2 xx = x2[gi];
        float2 r;
        r.x = xx.x + fmaxf(wacc.x * dnw + bb.x, 0.f);
        r.y = xx.y + fmaxf(wacc.y * dnw + bb.y, 0.f);
        o2[gi] = r;
    }
}

extern "C" void kernel_launch(void* const* d_in, const int* in_sizes, int n_in,
                              void* d_out, int out_size, void* d_ws, size_t ws_size,
                              hipStream_t stream) {
    const float* x = (const float*)d_in[0];
    const int* ei  = (const int*)d_in[1];
    const float* W = (const float*)d_in[2];
    const float* b = (const float*)d_in[3];
    float* out = (float*)d_out;

    int N = in_sizes[0] / DIM;
    int E = in_sizes[1] / 2;
    int nbuck = (N + NPB - 1) / NPB;  // 391

    char* ws = (char*)d_ws;
    size_t o = 0;
    unsigned short* hbf = (unsigned short*)(ws + o); o += (size_t)N * DIM * sizeof(unsigned short);
    float* dinv  = (float*)(ws + o); o += (size_t)N * sizeof(float);
    int*   off   = (int*)(ws + o);   o += (size_t)N * sizeof(int);
    int*   ncnt  = (int*)(ws + o);   o += (size_t)N * sizeof(int);
    int*   bcur  = (int*)(ws + o);   o += (size_t)nbuck * BSTRIDE * sizeof(int);
    unsigned* binned = (unsigned*)(ws + o); o += (size_t)nbuck * BCAP * sizeof(unsigned);
    int*   adj   = (int*)(ws + o);   o += (size_t)nbuck * BCAP * sizeof(int);

    int binB = (E + CHUNK - 1) / CHUNK;          // 391 binning blocks (first)
    int mmB  = (N + 63) / 64;                    // 1563 matmul blocks

    hipMemsetAsync(bcur, 0, (size_t)nbuck * BSTRIDE * sizeof(int), stream);
    fused_mm_bin<<<binB + mmB, 256, 0, stream>>>(x, W, hbf, N, ei, bcur,
                                                 binned, E, nbuck, binB);
    bucket_sort<<<nbuck, 512, 0, stream>>>(bcur, binned, off, ncnt, adj, dinv, N);
    gather_agg<<<(N + 7) / 8, 256, 0, stream>>>(off, ncnt, adj, (const unsigned*)hbf, dinv,
                                                (const float2*)x, (const float2*)b,
                                                (float2*)out, N);
}